// Round 7
// baseline (124.736 us; speedup 1.0000x reference)
//
#include <hip/hip_runtime.h>
#include <math.h>

#define NUM_FREQS 10
#define EDIM 60            // 3 * 2 * NUM_FREQS
#define TRADEOFF 1.0f

typedef __attribute__((ext_vector_type(8))) short bf16x8;
typedef __attribute__((ext_vector_type(4))) float f32x4;

// float -> bf16 (RNE) native cast
__device__ __forceinline__ short bfc(float f) {
    return __builtin_bit_cast(short, (__bf16)f);
}

// xor16 lane exchange via ds_swizzle (BitMode: offset = (xor<<10)|(or<<5)|and)
__device__ __forceinline__ float swz16(float x) {
    return __builtin_bit_cast(float,
        __builtin_amdgcn_ds_swizzle(__builtin_bit_cast(int, x), 0x401F));
}
// xor32 (crosses 32-lane halves)
__device__ __forceinline__ float sx32(float x) { return __shfl_xor(x, 32, 64); }

// NeRF posenc, layout enc[l*6 + s*3 + d] (s=0 sin, s=1 cos).
// Hardware sin/cos in revolutions; exact arg doubling per frequency.
__device__ __forceinline__ void posenc3(float x0, float x1, float x2, float* enc) {
    const float inv2pi = 0.15915494309189535f;
    float xs[3] = {x0, x1, x2};
#pragma unroll
    for (int d = 0; d < 3; ++d) {
        float xr = xs[d] * inv2pi;
#pragma unroll
        for (int l = 0; l < NUM_FREQS; ++l) {
            const float fr = __builtin_amdgcn_fractf(xr);
            enc[l*6 + d]     = __builtin_amdgcn_sinf(fr);
            enc[l*6 + 3 + d] = __builtin_amdgcn_cosf(fr);
            xr *= 2.0f;   // exact
        }
    }
}

// Barrier-free persistent kernel. 256 threads = 4 independent waves.
// sW rows r = 4c+ch (ch 0..2 rgb, 3 score). MFMA m-subtile t ->
// lane (g,l15) accumulator acc[t][rg] = row 16t+4g+rg = cluster 4t+g, channel rg,
// point l15. So each lane holds 16 full clusters for one point: softmax is
// lane-local + 2 butterfly rounds across g (xor16 swizzle, xor32 shfl).
// Wave w owns points 64w..64w+63 of each chunk -> private sA region, no barriers.
__global__ __launch_bounds__(256) void fused3(
        const float* __restrict__ X,
        const int*   __restrict__ cluster_ids,
        const float* __restrict__ lm,      // [192, 60]
        const float* __restrict__ Wq,      // [5, 60]
        const float* __restrict__ Wk,      // [5, 60]
        const float* __restrict__ Wv,      // [3, 3]
        const float* __restrict__ cents,   // [64, 3]
        float* __restrict__ out,
        int N, int nChunks) {
    __shared__ __align__(16) unsigned short sW[256 * 64];  // 32 KB, slot-swizzled
    __shared__ __align__(16) unsigned short sA[256 * 64];  // 32 KB, per-wave 64-row regions
    __shared__ int sCid[256];

    const int tid  = threadIdx.x;
    const int lane = tid & 63;
    const int w    = tid >> 6;
    const int g    = lane >> 4;
    const int l15  = lane & 15;
    const int wbase = w * 64;

    // ================= prologue: build sW (once per block) =================
    {
        const int r = tid, c = r >> 2, ch = r & 3;
        float row[64];
#pragma unroll
        for (int k = 0; k < 64; ++k) row[k] = 0.f;
        if (ch < 3) {
            const float* src = lm + (3*c + ch) * EDIM;
            for (int k = 0; k < EDIM; ++k) row[k] = src[k];
        } else {
            float enc[EDIM];
            posenc3(cents[c*3+0], cents[c*3+1], cents[c*3+2], enc);
            const float isd = 0.4472135954999579f;  // 1/sqrt(5)
            float kq[5];
#pragma unroll
            for (int j = 0; j < 5; ++j) {
                float a = 0.f;
                for (int k = 0; k < EDIM; ++k) a = fmaf(enc[k], Wk[j*EDIM + k], a);
                kq[j] = a * isd;
            }
            for (int k = 0; k < EDIM; ++k)
                row[k] = Wq[0*EDIM+k]*kq[0] + Wq[1*EDIM+k]*kq[1] + Wq[2*EDIM+k]*kq[2]
                       + Wq[3*EDIM+k]*kq[3] + Wq[4*EDIM+k]*kq[4];
        }
#pragma unroll
        for (int u8 = 0; u8 < 8; ++u8) {
            const int slot = u8 ^ (r & 7);
            bf16x8 v;
#pragma unroll
            for (int j = 0; j < 8; ++j) v[j] = bfc(row[u8*8 + j]);
            *(bf16x8*)&sW[r*64 + slot*8] = v;
        }
    }
    const float wv00 = Wv[0], wv01 = Wv[1], wv02 = Wv[2];
    const float wv10 = Wv[3], wv11 = Wv[4], wv12 = Wv[5];
    const float wv20 = Wv[6], wv21 = Wv[7], wv22 = Wv[8];

    __syncthreads();   // the ONLY block-wide barrier

    float* o_out = out;
    float* o_km  = out + (size_t)N * 3;
    float* o_at  = out + (size_t)N * 6;

    // ================= chunk loop (waves fully independent) =================
    for (int chunk = blockIdx.x; chunk < nChunks; chunk += gridDim.x) {
        const int base = chunk << 8;

        // own-point posenc -> private sA rows (bf16, 16B-slot XOR swizzle)
        {
            int n = base + tid; if (n >= N) n = N - 1;
            sCid[tid] = cluster_ids[n];
            float enc[64];
            posenc3(X[n*3+0], X[n*3+1], X[n*3+2], enc);
            enc[60] = 0.f; enc[61] = 0.f; enc[62] = 0.f; enc[63] = 0.f;
#pragma unroll
            for (int u8 = 0; u8 < 8; ++u8) {
                const int slot = u8 ^ (tid & 7);
                bf16x8 v;
#pragma unroll
                for (int j = 0; j < 8; ++j) v[j] = bfc(enc[u8*8 + j]);
                *(bf16x8*)&sA[tid*64 + slot*8] = v;
            }
        }
        // same-wave LDS produce->consume: DS in-order per wave, no barrier.

        for (int h = 0; h < 2; ++h) {
            // B-fragments for subtiles 2h, 2h+1 (points wbase + si*16 + l15)
            bf16x8 b0[2], b1[2];
#pragma unroll
            for (int kf = 0; kf < 2; ++kf) {
                const int slot = (kf*4 + g) ^ (l15 & 7);
                b0[kf] = *(const bf16x8*)&sA[(wbase + (2*h  )*16 + l15)*64 + slot*8];
                b1[kf] = *(const bf16x8*)&sA[(wbase + (2*h+1)*16 + l15)*64 + slot*8];
            }
            // A-stream (shared by both subtiles) + MFMA
            f32x4 acc0[16], acc1[16];
#pragma unroll
            for (int t = 0; t < 16; ++t) {
                const int row = 16*t + l15;
                const bf16x8 a0 = *(const bf16x8*)&sW[row*64 + (( g   ) ^ (l15 & 7))*8];
                const bf16x8 a1 = *(const bf16x8*)&sW[row*64 + ((4+g) ^ (l15 & 7))*8];
                const f32x4 z = (f32x4){0.f, 0.f, 0.f, 0.f};
                acc0[t] = __builtin_amdgcn_mfma_f32_16x16x32_bf16(a1, b0[1],
                          __builtin_amdgcn_mfma_f32_16x16x32_bf16(a0, b0[0], z, 0,0,0), 0,0,0);
                acc1[t] = __builtin_amdgcn_mfma_f32_16x16x32_bf16(a1, b1[1],
                          __builtin_amdgcn_mfma_f32_16x16x32_bf16(a0, b1[0], z, 0,0,0), 0,0,0);
            }

            // ---- combine both subtiles fully in-wave
#pragma unroll
            for (int u = 0; u < 2; ++u) {
                const f32x4* acc = (u == 0) ? acc0 : acc1;  // static after unroll
                const int si = 2*h + u;
                const int pl = si*16 + l15;
                const int cid = sCid[wbase + pl];

                float mx = fmaxf(
                    fmaxf(fmaxf(fmaxf(acc[0][3], acc[1][3]), fmaxf(acc[2][3], acc[3][3])),
                          fmaxf(fmaxf(acc[4][3], acc[5][3]), fmaxf(acc[6][3], acc[7][3]))),
                    fmaxf(fmaxf(fmaxf(acc[8][3], acc[9][3]), fmaxf(acc[10][3], acc[11][3])),
                          fmaxf(fmaxf(acc[12][3], acc[13][3]), fmaxf(acc[14][3], acc[15][3]))));
                mx = fmaxf(mx, swz16(mx));
                mx = fmaxf(mx, sx32(mx));

                float S = 0.f, a0s = 0.f, a1s = 0.f, a2s = 0.f;
                float k0 = 0.f, k1 = 0.f, k2 = 0.f;
                const bool gm = ((cid & 3) == g);
                const int  ct = cid >> 2;
#pragma unroll
                for (int t = 0; t < 16; ++t) {
                    const float e = __expf(acc[t][3] - mx);
                    S += e;
                    a0s = fmaf(e, acc[t][0], a0s);
                    a1s = fmaf(e, acc[t][1], a1s);
                    a2s = fmaf(e, acc[t][2], a2s);
                    const bool sel = gm && (ct == t);
                    k0 = sel ? acc[t][0] : k0;
                    k1 = sel ? acc[t][1] : k1;
                    k2 = sel ? acc[t][2] : k2;
                }
                // cross-g butterfly (xor16 + xor32)
                S   += swz16(S);   a0s += swz16(a0s); a1s += swz16(a1s); a2s += swz16(a2s);
                k0  += swz16(k0);  k1  += swz16(k1);  k2  += swz16(k2);
                S   += sx32(S);    a0s += sx32(a0s);  a1s += sx32(a1s);  a2s += sx32(a2s);
                k0  += sx32(k0);   k1  += sx32(k1);   k2  += sx32(k2);

                const int n = base + wbase + pl;
                if (g == 0 && n < N) {
                    const float inv = 1.0f / S;
                    const float u0 = a0s*inv, u1 = a1s*inv, u2 = a2s*inv;
                    const float at0 = wv00*u0 + wv01*u1 + wv02*u2;
                    const float at1 = wv10*u0 + wv11*u1 + wv12*u2;
                    const float at2 = wv20*u0 + wv21*u1 + wv22*u2;
                    const float oo0 = k0*TRADEOFF + at0*(1.0f - TRADEOFF);
                    const float oo1 = k1*TRADEOFF + at1*(1.0f - TRADEOFF);
                    const float oo2 = k2*TRADEOFF + at2*(1.0f - TRADEOFF);
                    o_out[n*3+0] = oo0; o_out[n*3+1] = oo1; o_out[n*3+2] = oo2;
                    o_km[n*3+0]  = k0;  o_km[n*3+1]  = k1;  o_km[n*3+2]  = k2;
                    o_at[n*3+0]  = at0; o_at[n*3+1]  = at1; o_at[n*3+2]  = at2;
                }
            }
        }
    }
}

extern "C" void kernel_launch(void* const* d_in, const int* in_sizes, int n_in,
                              void* d_out, int out_size, void* d_ws, size_t ws_size,
                              hipStream_t stream) {
    const float* X         = (const float*)d_in[0];
    const int*   cids      = (const int*)  d_in[1];
    const float* lm        = (const float*)d_in[2];
    const float* Wq        = (const float*)d_in[3];
    const float* Wk        = (const float*)d_in[4];
    const float* Wv        = (const float*)d_in[5];
    const float* centroids = (const float*)d_in[6];
    float* out = (float*)d_out;
    const int N = in_sizes[0] / 3;

    const int nChunks = (N + 255) / 256;
    const int grid = nChunks < 512 ? nChunks : 512;   // 2 blocks/CU (66.5 KB LDS)
    fused3<<<grid, 256, 0, stream>>>(X, cids, lm, Wq, Wk, Wv, centroids, out, N, nChunks);
}